// Round 2
// baseline (307.394 us; speedup 1.0000x reference)
//
#include <hip/hip_runtime.h>

// B=8, N1=8192, N2=2048, C1=128, C2=256, O1=O2=256, IN_CH=384
typedef __attribute__((ext_vector_type(8))) short bf16x8;
typedef __attribute__((ext_vector_type(4))) float f32x4;
typedef __attribute__((ext_vector_type(4))) unsigned short u16x4;

__device__ __forceinline__ unsigned short f2bf(float f) {
  unsigned u = __float_as_uint(f);
  u += 0x7FFFu + ((u >> 16) & 1u);   // RNE to bf16
  return (unsigned short)(u >> 16);
}

// ---------------- pack W1/W2 into bf16 MFMA A-fragment-major -----------------
// wpk[((kt*16+mt)*64+lane)*8 + j] = W[mt*16+(lane&15)][kt*32+(lane>>4)*8+j]
__global__ __launch_bounds__(256) void pack_w(const float* __restrict__ W1,
                                              const float* __restrict__ W2,
                                              short* __restrict__ wpk1,
                                              short* __restrict__ wpk2) {
  int id = blockIdx.x * 256 + threadIdx.x;   // 640*256 = 163840 = 98304 + 65536
  if (id < 98304) {                          // W1: K=384 -> 12 ktiles
    int j = id & 7, lane = (id >> 3) & 63, mt = (id >> 9) & 15, kt = id >> 13;
    int o = mt * 16 + (lane & 15);
    int c = kt * 32 + ((lane >> 4) & 3) * 8 + j;
    wpk1[id] = (short)f2bf(W1[o * 384 + c]);
  } else {                                   // W2: K=256 -> 8 ktiles
    int f = id - 98304;
    int j = f & 7, lane = (f >> 3) & 63, mt = (f >> 9) & 15, kt = f >> 13;
    int o = mt * 16 + (lane & 15);
    int c = kt * 32 + ((lane >> 4) & 3) * 8 + j;
    wpk2[f] = (short)f2bf(W2[o * 256 + c]);
  }
}

// ---------------- feats2 [b][256][2048] f32 -> f2t [b][2048][256] f32 --------
__global__ __launch_bounds__(256) void transpose_f2(const float* __restrict__ f2,
                                                    float* __restrict__ f2t) {
  __shared__ float tile[64][65];
  int b = blockIdx.z, c0 = blockIdx.y * 64, j0 = blockIdx.x * 64;
  int t = threadIdx.x, tj = t & 63, tr = t >> 6;
#pragma unroll
  for (int p = 0; p < 16; ++p) {
    int ci = p * 4 + tr;
    tile[ci][tj] = f2[(size_t)(b * 256 + c0 + ci) * 2048 + j0 + tj];
  }
  __syncthreads();
#pragma unroll
  for (int p = 0; p < 16; ++p) {
    int jr = p * 4 + tr;
    f2t[(size_t)(b * 2048 + j0 + jr) * 256 + c0 + tj] = tile[tj][jr];
  }
}

// ---------------- feats1 [b][128][8192] f32 -> ft1 [b][8192][128] bf16 -------
__global__ __launch_bounds__(256) void transpose_f1(const float* __restrict__ f1,
                                                    short* __restrict__ ft1) {
  __shared__ float tile[64][65];
  int b = blockIdx.z, c0 = blockIdx.y * 64, j0 = blockIdx.x * 64;
  int t = threadIdx.x, tj = t & 63, tr = t >> 6;
#pragma unroll
  for (int p = 0; p < 16; ++p) {
    int ci = p * 4 + tr;
    tile[ci][tj] = f1[(size_t)(b * 128 + c0 + ci) * 8192 + j0 + tj];
  }
  __syncthreads();
#pragma unroll
  for (int p = 0; p < 16; ++p) {
    int jr = p * 4 + tr;
    ft1[((size_t)b * 8192 + j0 + jr) * 128 + c0 + tj] = (short)f2bf(tile[tj][jr]);
  }
}

// ---------------- register-resident 4-way merge helpers ----------------------
__device__ __forceinline__ void merge44(
    float a0, float a1, float a2, float a3, int x0, int x1, int x2, int x3,
    float c0, float c1, float c2, float c3, int y0, int y1, int y2, int y3,
    float& o0, float& o1, float& o2, float& o3, int& p0, int& p1, int& p2, int& p3) {
  float od0, od1, od2, od3; int oi0, oi1, oi2, oi3;
#define POP(OD, OI)                                                        \
  {                                                                        \
    bool s = (a0 < c0) || ((a0 == c0) && (x0 < y0));                       \
    OD = s ? a0 : c0; OI = s ? x0 : y0;                                    \
    float sa0 = s ? a1 : a0, sa1 = s ? a2 : a1, sa2 = s ? a3 : a2;         \
    int   sx0 = s ? x1 : x0, sx1 = s ? x2 : x1, sx2 = s ? x3 : x2;         \
    float sc0 = s ? c0 : c1, sc1 = s ? c1 : c2, sc2 = s ? c2 : c3;         \
    int   sy0 = s ? y0 : y1, sy1 = s ? y1 : y2, sy2 = s ? y2 : y3;         \
    a3 = s ? 3.4e38f : a3; c3 = s ? c3 : 3.4e38f;                          \
    a0 = sa0; a1 = sa1; a2 = sa2; x0 = sx0; x1 = sx1; x2 = sx2;            \
    c0 = sc0; c1 = sc1; c2 = sc2; y0 = sy0; y1 = sy1; y2 = sy2;            \
  }
  POP(od0, oi0) POP(od1, oi1) POP(od2, oi2) POP(od3, oi3)
#undef POP
  o0 = od0; o1 = od1; o2 = od2; o3 = od3;
  p0 = oi0; p1 = oi1; p2 = oi2; p3 = oi3;
}

// ---------------- fused: KNN + interp + concat + 2x (GEMM+BN+ReLU) ----------
// One block = 64 queries of one batch. LDS: SA(32K): t4 scratch -> X-tile;
// SB(32K): candidate pts -> w3/id3 -> H1 tile.
__global__ __launch_bounds__(256) void fused(
    const float* __restrict__ xyz1, const float* __restrict__ xyz2,
    const float* __restrict__ f2t, const short* __restrict__ ft1,
    const short* __restrict__ wpk1, const short* __restrict__ wpk2,
    const float* __restrict__ b1, const float* __restrict__ g1, const float* __restrict__ be1,
    const float* __restrict__ b2, const float* __restrict__ g2, const float* __restrict__ be2,
    float* __restrict__ out) {
  __shared__ __align__(16) char SA[32768];
  __shared__ __align__(16) char SB[32768];
  const int t = threadIdx.x, lane = t & 63, wid = t >> 6;
  const int b = blockIdx.y, n0 = blockIdx.x * 64;
  const int l15 = lane & 15, l4 = lane >> 4;

  // phase 0: stage {x,y,z,|p|^2} for all 2048 candidates into SB (exact np order)
  {
    float4* pkB = (float4*)SB;
    for (int j = t; j < 2048; j += 256) {
      const float* p = xyz2 + ((size_t)b * 2048 + j) * 3;
      float px = p[0], py = p[1], pz = p[2];
      float s2 = __fadd_rn(__fadd_rn(__fmul_rn(px, px), __fmul_rn(py, py)), __fmul_rn(pz, pz));
      pkB[j] = make_float4(px, py, pz, s2);
    }
  }
  const int qq = t & 63, seg = t >> 6;
  float qx, qy, qz, s1;
  {
    const float* p = xyz1 + ((size_t)b * 8192 + n0 + qq) * 3;
    qx = p[0]; qy = p[1]; qz = p[2];
    s1 = __fadd_rn(__fadd_rn(__fmul_rn(qx, qx), __fmul_rn(qy, qy)), __fmul_rn(qz, qz));
  }
  __syncthreads();

  // phase 1: scan my 512-candidate segment, keep top-4 by (d2, idx)
  float bd0 = 3.4e38f, bd1 = 3.4e38f, bd2 = 3.4e38f, bd3 = 3.4e38f;
  int bi0 = 0, bi1 = 0, bi2 = 0, bi3 = 0;
  {
    const float4* pkB = (const float4*)SB;
    int jb = seg * 512;
#pragma unroll 2
    for (int j = jb; j < jb + 512; ++j) {
      float4 P = pkB[j];
      float dot = __fadd_rn(__fadd_rn(__fmul_rn(qx, P.x), __fmul_rn(qy, P.y)), __fmul_rn(qz, P.z));
      float d2 = __fsub_rn(__fadd_rn(s1, P.w), __fadd_rn(dot, dot));
      if (d2 < bd3) {               // strict < keeps earliest index on ties
        if (d2 < bd2) {
          bd3 = bd2; bi3 = bi2;
          if (d2 < bd1) {
            bd2 = bd1; bi2 = bi1;
            if (d2 < bd0) { bd1 = bd0; bi1 = bi0; bd0 = d2; bi0 = j; }
            else          { bd1 = d2;  bi1 = j; }
          } else { bd2 = d2; bi2 = j; }
        } else { bd3 = d2; bi3 = j; }
      }
    }
  }
  {
    float4* t4d = (float4*)SA;
    int4*   t4i = (int4*)(SA + 4096);
    t4d[t] = make_float4(bd0, bd1, bd2, bd3);
    t4i[t] = make_int4(bi0, bi1, bi2, bi3);
  }
  __syncthreads();

  // phase 2: threads 0..63 merge 4 segment lists, sqrt, (d,idx)-stable sort, weights
  if (t < 64) {
    const float4* t4d = (const float4*)SA;
    const int4*   t4i = (const int4*)(SA + 4096);
    float4 da = t4d[t], db = t4d[64 + t], dc = t4d[128 + t], dd = t4d[192 + t];
    int4   ia = t4i[t], ib = t4i[64 + t], ic = t4i[128 + t], id = t4i[192 + t];
    float ma0, ma1, ma2, ma3, mb0, mb1, mb2, mb3, m0, m1, m2, m3;
    int   na0, na1, na2, na3, nb0, nb1, nb2, nb3, q0i, q1i, q2i, q3i;
    merge44(da.x, da.y, da.z, da.w, ia.x, ia.y, ia.z, ia.w,
            db.x, db.y, db.z, db.w, ib.x, ib.y, ib.z, ib.w,
            ma0, ma1, ma2, ma3, na0, na1, na2, na3);
    merge44(dc.x, dc.y, dc.z, dc.w, ic.x, ic.y, ic.z, ic.w,
            dd.x, dd.y, dd.z, dd.w, id.x, id.y, id.z, id.w,
            mb0, mb1, mb2, mb3, nb0, nb1, nb2, nb3);
    merge44(ma0, ma1, ma2, ma3, na0, na1, na2, na3,
            mb0, mb1, mb2, mb3, nb0, nb1, nb2, nb3,
            m0, m1, m2, m3, q0i, q1i, q2i, q3i);
    float e0 = __fsqrt_rn(fmaxf(m0, 0.0f));
    float e1 = __fsqrt_rn(fmaxf(m1, 0.0f));
    float e2 = __fsqrt_rn(fmaxf(m2, 0.0f));
    float e3 = __fsqrt_rn(fmaxf(m3, 0.0f));
#define SW(DX, IX, DY, IY)                                                \
  {                                                                       \
    bool sw = (DX > DY) || ((DX == DY) && (IX > IY));                     \
    float td = DX; int ti = IX;                                           \
    DX = sw ? DY : DX; IX = sw ? IY : IX;                                 \
    DY = sw ? td : DY; IY = sw ? ti : IY;                                 \
  }
    SW(e0, q0i, e1, q1i) SW(e1, q1i, e2, q2i) SW(e2, q2i, e3, q3i)
    SW(e0, q0i, e1, q1i) SW(e1, q1i, e2, q2i)
    SW(e0, q0i, e1, q1i)
#undef SW
    float k0 = fmaxf(e0, 1e-8f), k1 = fmaxf(e1, 1e-8f), k2 = fmaxf(e2, 1e-8f);
    float u0 = 1.0f / k0, u1 = 1.0f / k1, u2 = 1.0f / k2;
    float ss = __fadd_rn(__fadd_rn(u0, u1), u2);
    float* w3 = (float*)SB;           // SB[0:768)
    int*  id3 = (int*)(SB + 768);     // SB[768:1536)  (candidate region is dead now)
    w3[t * 3 + 0] = u0 / ss; w3[t * 3 + 1] = u1 / ss; w3[t * 3 + 2] = u2 / ss;
    id3[t * 3 + 0] = q0i; id3[t * 3 + 1] = q1i; id3[t * 3 + 2] = q2i;
  }
  __syncthreads();

  // phase 3: interpolation -> X-tile in SA: bf16 [64 rows][256 ch], XOR-swizzled
  {
    const float* w3 = (const float*)SB;
    const int*  id3 = (const int*)(SB + 768);
    const size_t f2b = (size_t)b * 2048 * 256;
#pragma unroll 2
    for (int q = 0; q < 64; ++q) {
      int j0 = id3[q * 3 + 0], j1 = id3[q * 3 + 1], j2 = id3[q * 3 + 2];
      float W0 = w3[q * 3 + 0], W1v = w3[q * 3 + 1], W2v = w3[q * 3 + 2];
      float v0 = f2t[f2b + (size_t)j0 * 256 + t];   // t = channel, 1KB coalesced
      float v1 = f2t[f2b + (size_t)j1 * 256 + t];
      float v2 = f2t[f2b + (size_t)j2 * 256 + t];
      float v = W0 * v0 + W1v * v1 + W2v * v2;
      int addr = (q * 512 + t * 2) ^ ((q & 7) << 4);
      *(unsigned short*)(SA + addr) = f2bf(v);
    }
  }
  __syncthreads();

  // phase 4: GEMM1 (K=384 = 256 interp from LDS + 128 feats1 from global)
  f32x4 acc[4][4];
#pragma unroll
  for (int m = 0; m < 4; ++m)
#pragma unroll
    for (int n = 0; n < 4; ++n) acc[m][n] = (f32x4){0.f, 0.f, 0.f, 0.f};

#pragma unroll
  for (int kt = 0; kt < 8; ++kt) {   // interp part (LDS)
    bf16x8 a[4], bb[4];
#pragma unroll
    for (int m = 0; m < 4; ++m)
      a[m] = *(const bf16x8*)(wpk1 + ((size_t)(kt * 16 + wid * 4 + m) * 64 + lane) * 8);
#pragma unroll
    for (int nt = 0; nt < 4; ++nt) {
      int q = nt * 16 + l15;
      int addr = q * 512 + ((kt * 64 + l4 * 16) ^ ((q & 7) << 4));
      bb[nt] = *(const bf16x8*)(SA + addr);
    }
#pragma unroll
    for (int m = 0; m < 4; ++m)
#pragma unroll
      for (int nt = 0; nt < 4; ++nt)
        acc[m][nt] = __builtin_amdgcn_mfma_f32_16x16x32_bf16(a[m], bb[nt], acc[m][nt], 0, 0, 0);
  }
#pragma unroll
  for (int kt = 8; kt < 12; ++kt) {  // feats1 part (global, bf16 [n][128])
    bf16x8 a[4], bb[4];
#pragma unroll
    for (int m = 0; m < 4; ++m)
      a[m] = *(const bf16x8*)(wpk1 + ((size_t)(kt * 16 + wid * 4 + m) * 64 + lane) * 8);
#pragma unroll
    for (int nt = 0; nt < 4; ++nt)
      bb[nt] = *(const bf16x8*)(ft1 + ((size_t)b * 8192 + n0 + nt * 16 + l15) * 128 +
                                (kt - 8) * 32 + l4 * 8);
#pragma unroll
    for (int m = 0; m < 4; ++m)
#pragma unroll
      for (int nt = 0; nt < 4; ++nt)
        acc[m][nt] = __builtin_amdgcn_mfma_f32_16x16x32_bf16(a[m], bb[nt], acc[m][nt], 0, 0, 0);
  }

  // epilogue 1: H1 = relu(bn(acc+b1)) -> SB as bf16 [64][256] swizzled
  const float BNINV = 0.99999500003749972f;   // 1/sqrt(1+1e-5)
#pragma unroll
  for (int m = 0; m < 4; ++m) {
    int cb = wid * 64 + m * 16 + l4 * 4;
    float gv[4], bv[4], ev[4];
#pragma unroll
    for (int r = 0; r < 4; ++r) {
      gv[r] = g1[cb + r] * BNINV; bv[r] = b1[cb + r]; ev[r] = be1[cb + r];
    }
#pragma unroll
    for (int nt = 0; nt < 4; ++nt) {
      int q = nt * 16 + l15;
      u16x4 pk4;
#pragma unroll
      for (int r = 0; r < 4; ++r)
        pk4[r] = f2bf(fmaxf((acc[m][nt][r] + bv[r]) * gv[r] + ev[r], 0.0f));
      *(u16x4*)(SB + ((q * 512 + cb * 2) ^ ((q & 7) << 4))) = pk4;
    }
  }
  __syncthreads();

  // phase 5: GEMM2 (K=256 from SB)
#pragma unroll
  for (int m = 0; m < 4; ++m)
#pragma unroll
    for (int n = 0; n < 4; ++n) acc[m][n] = (f32x4){0.f, 0.f, 0.f, 0.f};
#pragma unroll
  for (int kt = 0; kt < 8; ++kt) {
    bf16x8 a[4], bb[4];
#pragma unroll
    for (int m = 0; m < 4; ++m)
      a[m] = *(const bf16x8*)(wpk2 + ((size_t)(kt * 16 + wid * 4 + m) * 64 + lane) * 8);
#pragma unroll
    for (int nt = 0; nt < 4; ++nt) {
      int q = nt * 16 + l15;
      int addr = q * 512 + ((kt * 64 + l4 * 16) ^ ((q & 7) << 4));
      bb[nt] = *(const bf16x8*)(SB + addr);
    }
#pragma unroll
    for (int m = 0; m < 4; ++m)
#pragma unroll
      for (int nt = 0; nt < 4; ++nt)
        acc[m][nt] = __builtin_amdgcn_mfma_f32_16x16x32_bf16(a[m], bb[nt], acc[m][nt], 0, 0, 0);
  }

  // epilogue 2: out = relu(bn(acc+b2)) -> d_out f32 [b][o][n]
#pragma unroll
  for (int m = 0; m < 4; ++m) {
    int ob = wid * 64 + m * 16 + l4 * 4;
    float gv[4], bv[4], ev[4];
#pragma unroll
    for (int r = 0; r < 4; ++r) {
      gv[r] = g2[ob + r] * BNINV; bv[r] = b2[ob + r]; ev[r] = be2[ob + r];
    }
#pragma unroll
    for (int nt = 0; nt < 4; ++nt) {
      int nn = n0 + nt * 16 + l15;
#pragma unroll
      for (int r = 0; r < 4; ++r)
        out[((size_t)b * 256 + ob + r) * 8192 + nn] =
            fmaxf((acc[m][nt][r] + bv[r]) * gv[r] + ev[r], 0.0f);
    }
  }
}

extern "C" void kernel_launch(void* const* d_in, const int* in_sizes, int n_in,
                              void* d_out, int out_size, void* d_ws, size_t ws_size,
                              hipStream_t stream) {
  (void)in_sizes; (void)n_in; (void)out_size; (void)ws_size;
  const float* xyz1   = (const float*)d_in[0];
  const float* xyz2   = (const float*)d_in[1];
  const float* feats1 = (const float*)d_in[2];
  const float* feats2 = (const float*)d_in[3];
  const float* W1  = (const float*)d_in[4];
  const float* b1  = (const float*)d_in[5];
  const float* g1  = (const float*)d_in[6];
  const float* be1 = (const float*)d_in[7];
  const float* W2  = (const float*)d_in[8];
  const float* b2  = (const float*)d_in[9];
  const float* g2  = (const float*)d_in[10];
  const float* be2 = (const float*)d_in[11];
  float* out = (float*)d_out;

  // ws layout (33,882,112 B total):
  //   [0,       196608)    wpk1 bf16
  //   [196608,  327680)    wpk2 bf16
  //   [327680,  17104896)  f2t  f32  [8][2048][256]
  //   [17104896,33882112)  ft1  bf16 [8][8192][128]
  char* ws = (char*)d_ws;
  short* wpk1 = (short*)(ws);
  short* wpk2 = (short*)(ws + 196608);
  float* f2t  = (float*)(ws + 327680);
  short* ft1  = (short*)(ws + 17104896);

  pack_w<<<640, 256, 0, stream>>>(W1, W2, wpk1, wpk2);
  transpose_f2<<<dim3(32, 4, 8), 256, 0, stream>>>(feats2, f2t);
  transpose_f1<<<dim3(128, 2, 8), 256, 0, stream>>>(feats1, ft1);
  fused<<<dim3(128, 8), 256, 0, stream>>>(xyz1, xyz2, f2t, ft1, wpk1, wpk2,
                                          b1, g1, be1, b2, g2, be2, out);
}

// Round 3
// 231.465 us; speedup vs baseline: 1.3280x; 1.3280x over previous
//
#include <hip/hip_runtime.h>

// B=8, N1=8192, N2=2048, C1=128, C2=256, O1=O2=256, IN_CH=384
typedef __attribute__((ext_vector_type(8))) short bf16x8;
typedef __attribute__((ext_vector_type(4))) float f32x4;
typedef __attribute__((ext_vector_type(4))) unsigned short u16x4;

__device__ __forceinline__ unsigned short f2bf(float f) {
  unsigned u = __float_as_uint(f);
  u += 0x7FFFu + ((u >> 16) & 1u);   // RNE to bf16
  return (unsigned short)(u >> 16);
}

// ---------- prep: pack W1/W2 (bf16 A-frag-major) + transpose feats1/feats2 ---
// grid (464, 8): x<128 -> f2 transpose tile; 128<=x<384 -> f1 transpose tile;
// x>=384 -> pack_w slice (80 x 8 = 640 blocks of 256 ids).
__global__ __launch_bounds__(256) void prep(
    const float* __restrict__ f1, const float* __restrict__ f2,
    const float* __restrict__ W1, const float* __restrict__ W2,
    short* __restrict__ ft1, float* __restrict__ f2t,
    short* __restrict__ wpk1, short* __restrict__ wpk2) {
  __shared__ float tile[64][65];
  const int bx = blockIdx.x, b = blockIdx.y, t = threadIdx.x;
  const int tj = t & 63, tr = t >> 6;
  if (bx < 128) {            // feats2 [b][256][2048] -> f2t [b][2048][256] f32
    int j0 = (bx & 31) * 64, c0 = (bx >> 5) * 64;
#pragma unroll
    for (int p = 0; p < 16; ++p) {
      int ci = p * 4 + tr;
      tile[ci][tj] = f2[(size_t)(b * 256 + c0 + ci) * 2048 + j0 + tj];
    }
    __syncthreads();
#pragma unroll
    for (int p = 0; p < 16; ++p) {
      int jr = p * 4 + tr;
      f2t[(size_t)(b * 2048 + j0 + jr) * 256 + c0 + tj] = tile[tj][jr];
    }
  } else if (bx < 384) {     // feats1 [b][128][8192] -> ft1 [b][8192][128] bf16
    int i = bx - 128;
    int j0 = (i & 127) * 64, c0 = (i >> 7) * 64;
#pragma unroll
    for (int p = 0; p < 16; ++p) {
      int ci = p * 4 + tr;
      tile[ci][tj] = f1[(size_t)(b * 128 + c0 + ci) * 8192 + j0 + tj];
    }
    __syncthreads();
#pragma unroll
    for (int p = 0; p < 16; ++p) {
      int jr = p * 4 + tr;
      ft1[((size_t)b * 8192 + j0 + jr) * 128 + c0 + tj] = (short)f2bf(tile[tj][jr]);
    }
  } else {                   // pack weights
    int pb = (bx - 384) * 8 + b;          // 0..639
    int id = pb * 256 + t;                // 0..163839
    if (id < 98304) {                     // W1: K=384 -> 12 ktiles
      int j = id & 7, lane = (id >> 3) & 63, mt = (id >> 9) & 15, kt = id >> 13;
      int o = mt * 16 + (lane & 15);
      int c = kt * 32 + ((lane >> 4) & 3) * 8 + j;
      wpk1[id] = (short)f2bf(W1[o * 384 + c]);
    } else {                              // W2: K=256 -> 8 ktiles
      int f = id - 98304;
      int j = f & 7, lane = (f >> 3) & 63, mt = (f >> 9) & 15, kt = f >> 13;
      int o = mt * 16 + (lane & 15);
      int c = kt * 32 + ((lane >> 4) & 3) * 8 + j;
      wpk2[f] = (short)f2bf(W2[o * 256 + c]);
    }
  }
}

// ---------- 4-key ordered merge on packed f64 keys ---------------------------
__device__ __forceinline__ void merge44d(double a0, double a1, double a2, double a3,
                                         double c0, double c1, double c2, double c3,
                                         double& o0, double& o1, double& o2, double& o3) {
#define POP(OD)                                                           \
  {                                                                       \
    bool s = a0 < c0;                                                     \
    OD = s ? a0 : c0;                                                     \
    double sa0 = s ? a1 : a0, sa1 = s ? a2 : a1, sa2 = s ? a3 : a2;       \
    double sc0 = s ? c0 : c1, sc1 = s ? c1 : c2, sc2 = s ? c2 : c3;       \
    a3 = s ? 1e300 : a3; c3 = s ? c3 : 1e300;                             \
    a0 = sa0; a1 = sa1; a2 = sa2; c0 = sc0; c1 = sc1; c2 = sc2;           \
  }
  POP(o0) POP(o1) POP(o2) POP(o3)
#undef POP
}

// ---------- fused: KNN + interp + concat + 2x (GEMM+BN+ReLU) -----------------
// One block = 64 queries of one batch, 512 threads (8 waves).
// LDS: R1 32KB (candidates -> X-tile -> H1-tile), T4 16KB (scan keys),
//      W3/ID3 1.5KB.  Total 50.7KB -> 3 blocks/CU = 24 waves/CU.
__global__ __launch_bounds__(512) void fused(
    const float* __restrict__ xyz1, const float* __restrict__ xyz2,
    const float* __restrict__ f2t, const short* __restrict__ ft1,
    const short* __restrict__ wpk1, const short* __restrict__ wpk2,
    const float* __restrict__ b1, const float* __restrict__ g1, const float* __restrict__ be1,
    const float* __restrict__ b2, const float* __restrict__ g2, const float* __restrict__ be2,
    float* __restrict__ out) {
  __shared__ __align__(16) char R1[32768];
  __shared__ __align__(16) double T4[2048];   // [slot s][512 threads] -> T4[s*512+t]
  __shared__ float W3s[192];
  __shared__ int   ID3s[192];

  const int t = threadIdx.x, lane = t & 63, wid = t >> 6;
  const int b = blockIdx.y, n0 = blockIdx.x * 64;
  const int l15 = lane & 15, l4 = lane >> 4;

  // phase 0: stage {x,y,z,|p|^2} for 2048 candidates into R1 (exact np order)
  {
    float4* pkB = (float4*)R1;
    for (int j = t; j < 2048; j += 512) {
      const float* p = xyz2 + ((size_t)b * 2048 + j) * 3;
      float px = p[0], py = p[1], pz = p[2];
      float s2 = __fadd_rn(__fadd_rn(__fmul_rn(px, px), __fmul_rn(py, py)), __fmul_rn(pz, pz));
      pkB[j] = make_float4(px, py, pz, s2);
    }
  }
  const int qq = t & 63, seg = wid;   // wave w scans segment w for queries 0..63
  float qx, qy, qz, s1;
  {
    const float* p = xyz1 + ((size_t)b * 8192 + n0 + qq) * 3;
    qx = p[0]; qy = p[1]; qz = p[2];
    s1 = __fadd_rn(__fadd_rn(__fmul_rn(qx, qx), __fmul_rn(qy, qy)), __fmul_rn(qz, qz));
  }
  __syncthreads();

  // phase 1: branchless top-4 scan over my 256-candidate segment.
  // key = (double)(bits(max(d2,0))*2048 + j)  — exact, lexicographic (d2,idx).
  {
    double k0 = 1e300, k1 = 1e300, k2 = 1e300, k3 = 1e300;
    const float4* pkB = (const float4*)R1;
    int jb = seg * 256;
    double jd = (double)jb;
#pragma unroll 4
    for (int j = jb; j < jb + 256; ++j) {
      float4 P = pkB[j];
      float dot = __fadd_rn(__fadd_rn(__fmul_rn(qx, P.x), __fmul_rn(qy, P.y)), __fmul_rn(qz, P.z));
      float d2 = __fsub_rn(__fadd_rn(s1, P.w), __fadd_rn(dot, dot));
      float dc = fmaxf(d2, 0.0f);
      double K = fma((double)__float_as_uint(dc), 2048.0, jd);
      jd += 1.0;
      double t0 = fmax(k0, K); k0 = fmin(k0, K);
      double t1 = fmax(k1, t0); k1 = fmin(k1, t0);
      double t2 = fmax(k2, t1); k2 = fmin(k2, t1);
      k3 = fmin(k3, t2);
    }
    T4[0 * 512 + t] = k0; T4[1 * 512 + t] = k1;
    T4[2 * 512 + t] = k2; T4[3 * 512 + t] = k3;
  }
  __syncthreads();

  // phase 2: wave 0 merges the 8 segment lists per query, sqrt, stable re-sort,
  // weights.
  if (t < 64) {
    double l[8][4];
#pragma unroll
    for (int k = 0; k < 8; ++k)
#pragma unroll
      for (int s = 0; s < 4; ++s) l[k][s] = T4[s * 512 + k * 64 + t];
    double m01[4], m23[4], m45[4], m67[4], ma[4], mb[4], mf[4];
    merge44d(l[0][0], l[0][1], l[0][2], l[0][3], l[1][0], l[1][1], l[1][2], l[1][3],
             m01[0], m01[1], m01[2], m01[3]);
    merge44d(l[2][0], l[2][1], l[2][2], l[2][3], l[3][0], l[3][1], l[3][2], l[3][3],
             m23[0], m23[1], m23[2], m23[3]);
    merge44d(l[4][0], l[4][1], l[4][2], l[4][3], l[5][0], l[5][1], l[5][2], l[5][3],
             m45[0], m45[1], m45[2], m45[3]);
    merge44d(l[6][0], l[6][1], l[6][2], l[6][3], l[7][0], l[7][1], l[7][2], l[7][3],
             m67[0], m67[1], m67[2], m67[3]);
    merge44d(m01[0], m01[1], m01[2], m01[3], m23[0], m23[1], m23[2], m23[3],
             ma[0], ma[1], ma[2], ma[3]);
    merge44d(m45[0], m45[1], m45[2], m45[3], m67[0], m67[1], m67[2], m67[3],
             mb[0], mb[1], mb[2], mb[3]);
    merge44d(ma[0], ma[1], ma[2], ma[3], mb[0], mb[1], mb[2], mb[3],
             mf[0], mf[1], mf[2], mf[3]);
    // unpack (exact): key = dcbits*2048 + j
    float e[4]; int ji[4];
#pragma unroll
    for (int s = 0; s < 4; ++s) {
      double qd = mf[s] * (1.0 / 2048.0);       // exact (pow2 scale)
      double qf = trunc(qd);
      double jd = fma(-qf, 2048.0, mf[s]);      // exact j
      ji[s] = (int)jd;
      unsigned dcb = (unsigned)qf;
      e[s] = __fsqrt_rn(__uint_as_float(dcb));
    }
    // stable (d, idx) sort over 4 (handles sqrt-collapse ties like np top_k)
#define SW(X, Y)                                                          \
  {                                                                       \
    bool sw = (e[X] > e[Y]) || ((e[X] == e[Y]) && (ji[X] > ji[Y]));       \
    float td = e[X]; int ti = ji[X];                                      \
    e[X] = sw ? e[Y] : e[X]; ji[X] = sw ? ji[Y] : ji[X];                  \
    e[Y] = sw ? td : e[Y];   ji[Y] = sw ? ti : ji[Y];                     \
  }
    SW(0, 1) SW(1, 2) SW(2, 3) SW(0, 1) SW(1, 2) SW(0, 1)
#undef SW
    float k0 = fmaxf(e[0], 1e-8f), k1 = fmaxf(e[1], 1e-8f), k2 = fmaxf(e[2], 1e-8f);
    float u0 = 1.0f / k0, u1 = 1.0f / k1, u2 = 1.0f / k2;
    float ss = __fadd_rn(__fadd_rn(u0, u1), u2);
    W3s[t * 3 + 0] = u0 / ss; W3s[t * 3 + 1] = u1 / ss; W3s[t * 3 + 2] = u2 / ss;
    ID3s[t * 3 + 0] = ji[0]; ID3s[t * 3 + 1] = ji[1]; ID3s[t * 3 + 2] = ji[2];
  }
  __syncthreads();

  // phase 3: interpolation -> X-tile in R1: bf16 [64 rows][256 ch], XOR-swizzled
  {
    const int c = t & 255, half = t >> 8;     // two halves, 32 queries each
    const size_t f2b = (size_t)b * 2048 * 256;
#pragma unroll 2
    for (int qi = 0; qi < 32; ++qi) {
      int q = half * 32 + qi;
      int j0 = ID3s[q * 3 + 0], j1 = ID3s[q * 3 + 1], j2 = ID3s[q * 3 + 2];
      float W0 = W3s[q * 3 + 0], W1v = W3s[q * 3 + 1], W2v = W3s[q * 3 + 2];
      float v0 = f2t[f2b + (size_t)j0 * 256 + c];
      float v1 = f2t[f2b + (size_t)j1 * 256 + c];
      float v2 = f2t[f2b + (size_t)j2 * 256 + c];
      float v = W0 * v0 + W1v * v1 + W2v * v2;
      int addr = (q * 512 + c * 2) ^ ((q & 7) << 4);
      *(unsigned short*)(R1 + addr) = f2bf(v);
    }
  }
  __syncthreads();

  // phase 4: GEMM1 (K=384 = 256 interp from LDS + 128 feats1 from global).
  // 8 waves x 2 m-tiles = 256 output channels.
  f32x4 acc[2][4];
#pragma unroll
  for (int m = 0; m < 2; ++m)
#pragma unroll
    for (int n = 0; n < 4; ++n) acc[m][n] = (f32x4){0.f, 0.f, 0.f, 0.f};

#pragma unroll
  for (int kt = 0; kt < 8; ++kt) {   // interp part (LDS)
    bf16x8 a[2], bb[4];
#pragma unroll
    for (int m = 0; m < 2; ++m)
      a[m] = *(const bf16x8*)(wpk1 + ((size_t)(kt * 16 + wid * 2 + m) * 64 + lane) * 8);
#pragma unroll
    for (int nt = 0; nt < 4; ++nt) {
      int q = nt * 16 + l15;
      int addr = q * 512 + ((kt * 64 + l4 * 16) ^ ((q & 7) << 4));
      bb[nt] = *(const bf16x8*)(R1 + addr);
    }
#pragma unroll
    for (int m = 0; m < 2; ++m)
#pragma unroll
      for (int nt = 0; nt < 4; ++nt)
        acc[m][nt] = __builtin_amdgcn_mfma_f32_16x16x32_bf16(a[m], bb[nt], acc[m][nt], 0, 0, 0);
  }
#pragma unroll
  for (int kt = 8; kt < 12; ++kt) {  // feats1 part (global bf16 [n][128])
    bf16x8 a[2], bb[4];
#pragma unroll
    for (int m = 0; m < 2; ++m)
      a[m] = *(const bf16x8*)(wpk1 + ((size_t)(kt * 16 + wid * 2 + m) * 64 + lane) * 8);
#pragma unroll
    for (int nt = 0; nt < 4; ++nt)
      bb[nt] = *(const bf16x8*)(ft1 + ((size_t)b * 8192 + n0 + nt * 16 + l15) * 128 +
                                (kt - 8) * 32 + l4 * 8);
#pragma unroll
    for (int m = 0; m < 2; ++m)
#pragma unroll
      for (int nt = 0; nt < 4; ++nt)
        acc[m][nt] = __builtin_amdgcn_mfma_f32_16x16x32_bf16(a[m], bb[nt], acc[m][nt], 0, 0, 0);
  }
  __syncthreads();   // all reads of R1 (X) complete before H1 overwrites it

  // epilogue 1: H1 = relu(bn(acc+b1)) -> R1 as bf16 [64][256] swizzled
  const float BNINV = 0.99999500003749972f;   // 1/sqrt(1+1e-5)
#pragma unroll
  for (int m = 0; m < 2; ++m) {
    int cb = wid * 32 + m * 16 + l4 * 4;
    float gv[4], bv[4], ev[4];
#pragma unroll
    for (int r = 0; r < 4; ++r) {
      gv[r] = g1[cb + r] * BNINV; bv[r] = b1[cb + r]; ev[r] = be1[cb + r];
    }
#pragma unroll
    for (int nt = 0; nt < 4; ++nt) {
      int q = nt * 16 + l15;
      u16x4 pk4;
#pragma unroll
      for (int r = 0; r < 4; ++r)
        pk4[r] = f2bf(fmaxf((acc[m][nt][r] + bv[r]) * gv[r] + ev[r], 0.0f));
      *(u16x4*)(R1 + ((q * 512 + cb * 2) ^ ((q & 7) << 4))) = pk4;
    }
  }
  __syncthreads();

  // phase 5: GEMM2 (K=256 from R1)
#pragma unroll
  for (int m = 0; m < 2; ++m)
#pragma unroll
    for (int n = 0; n < 4; ++n) acc[m][n] = (f32x4){0.f, 0.f, 0.f, 0.f};
#pragma unroll
  for (int kt = 0; kt < 8; ++kt) {
    bf16x8 a[2], bb[4];
#pragma unroll
    for (int m = 0; m < 2; ++m)
      a[m] = *(const bf16x8*)(wpk2 + ((size_t)(kt * 16 + wid * 2 + m) * 64 + lane) * 8);
#pragma unroll
    for (int nt = 0; nt < 4; ++nt) {
      int q = nt * 16 + l15;
      int addr = q * 512 + ((kt * 64 + l4 * 16) ^ ((q & 7) << 4));
      bb[nt] = *(const bf16x8*)(R1 + addr);
    }
#pragma unroll
    for (int m = 0; m < 2; ++m)
#pragma unroll
      for (int nt = 0; nt < 4; ++nt)
        acc[m][nt] = __builtin_amdgcn_mfma_f32_16x16x32_bf16(a[m], bb[nt], acc[m][nt], 0, 0, 0);
  }

  // epilogue 2: out = relu(bn(acc+b2)) -> d_out f32 [b][o][n]
#pragma unroll
  for (int m = 0; m < 2; ++m) {
    int ob = wid * 32 + m * 16 + l4 * 4;
    float gv[4], bv[4], ev[4];
#pragma unroll
    for (int r = 0; r < 4; ++r) {
      gv[r] = g2[ob + r] * BNINV; bv[r] = b2[ob + r]; ev[r] = be2[ob + r];
    }
#pragma unroll
    for (int nt = 0; nt < 4; ++nt) {
      int nn = n0 + nt * 16 + l15;
#pragma unroll
      for (int r = 0; r < 4; ++r)
        out[((size_t)b * 256 + ob + r) * 8192 + nn] =
            fmaxf((acc[m][nt][r] + bv[r]) * gv[r] + ev[r], 0.0f);
    }
  }
}

extern "C" void kernel_launch(void* const* d_in, const int* in_sizes, int n_in,
                              void* d_out, int out_size, void* d_ws, size_t ws_size,
                              hipStream_t stream) {
  (void)in_sizes; (void)n_in; (void)out_size; (void)ws_size;
  const float* xyz1   = (const float*)d_in[0];
  const float* xyz2   = (const float*)d_in[1];
  const float* feats1 = (const float*)d_in[2];
  const float* feats2 = (const float*)d_in[3];
  const float* W1  = (const float*)d_in[4];
  const float* b1  = (const float*)d_in[5];
  const float* g1  = (const float*)d_in[6];
  const float* be1 = (const float*)d_in[7];
  const float* W2  = (const float*)d_in[8];
  const float* b2  = (const float*)d_in[9];
  const float* g2  = (const float*)d_in[10];
  const float* be2 = (const float*)d_in[11];
  float* out = (float*)d_out;

  // ws layout (33,882,112 B):
  //   [0,       196608)    wpk1 bf16
  //   [196608,  327680)    wpk2 bf16
  //   [327680,  17104896)  f2t  f32  [8][2048][256]
  //   [17104896,33882112)  ft1  bf16 [8][8192][128]
  char* ws = (char*)d_ws;
  short* wpk1 = (short*)(ws);
  short* wpk2 = (short*)(ws + 196608);
  float* f2t  = (float*)(ws + 327680);
  short* ft1  = (short*)(ws + 17104896);

  prep<<<dim3(464, 8), 256, 0, stream>>>(feats1, feats2, W1, W2, ft1, f2t, wpk1, wpk2);
  fused<<<dim3(128, 8), 512, 0, stream>>>(xyz1, xyz2, f2t, ft1, wpk1, wpk2,
                                          b1, g1, be1, b2, g2, be2, out);
}